// Round 14
// baseline (566.368 us; speedup 1.0000x reference)
//
#include <hip/hip_runtime.h>
#include <hip/hip_bf16.h>

#define T_TOK 16384
#define H_DIM 1024
#define FF_DIM 4096
#define NE 8
#define CAP 2048
#define EPS_F 1e-5f

#define BM2 256
#define BN2 256
#define BK2 32

typedef __attribute__((ext_vector_type(4))) float f32x4;
typedef __attribute__((ext_vector_type(16))) float f32x16;
typedef __attribute__((ext_vector_type(8))) short bf16x8;
typedef unsigned long long u64;
typedef unsigned int u32;

__device__ inline void gload_lds16(const void* g, void* l) {
  __builtin_amdgcn_global_load_lds(
      (const __attribute__((address_space(1))) unsigned int*)g,
      (__attribute__((address_space(3))) unsigned int*)l, 16, 0, 0);
}

__device__ inline unsigned short bf16_bits(float f) {
  __hip_bfloat16 h = __float2bfloat16(f);
  unsigned short u;
  __builtin_memcpy(&u, &h, 2);
  return u;
}

__device__ inline float bits_f32(unsigned short u) {
  const u32 x = ((u32)u) << 16;
  float f;
  __builtin_memcpy(&f, &x, 4);
  return f;
}

// ---- router: RMSNorm + logits + softmax + keys; zeroes tok_cnt; (EC=8) converts weights
__global__ __launch_bounds__(256) void router_kernel(
    const float* __restrict__ x, const float* __restrict__ nw,
    const float* __restrict__ rw, const float* __restrict__ rb,
    __hip_bfloat16* __restrict__ xn, u64* __restrict__ keys,
    int* __restrict__ tok_cnt,
    const float* __restrict__ w1s, __hip_bfloat16* __restrict__ w1d,
    const float* __restrict__ w2s, __hip_bfloat16* __restrict__ w2d, int do_cvt) {
  const int t = blockIdx.x;
  const int tid = threadIdx.x;
  if (tid == 0) tok_cnt[t] = 0;
  const float4 v = reinterpret_cast<const float4*>(x + (size_t)t * H_DIM)[tid];
  float ss = v.x * v.x + v.y * v.y + v.z * v.z + v.w * v.w;
#pragma unroll
  for (int o = 32; o > 0; o >>= 1) ss += __shfl_down(ss, o);
  __shared__ float red[4];
  __shared__ float redl[4][NE];
  const int wv = tid >> 6, ln = tid & 63;
  if (ln == 0) red[wv] = ss;
  __syncthreads();
  const float tot = red[0] + red[1] + red[2] + red[3];
  const float scale = rsqrtf(tot * (1.0f / H_DIM) + EPS_F);
  const float4 w4 = reinterpret_cast<const float4*>(nw)[tid];
  float xv0 = v.x * scale * w4.x, xv1 = v.y * scale * w4.y;
  float xv2 = v.z * scale * w4.z, xv3 = v.w * scale * w4.w;
  ushort4 u4;
  u4.x = bf16_bits(xv0); u4.y = bf16_bits(xv1);
  u4.z = bf16_bits(xv2); u4.w = bf16_bits(xv3);
  reinterpret_cast<ushort4*>(xn + (size_t)t * H_DIM)[tid] = u4;
  float lg[NE];
#pragma unroll
  for (int e = 0; e < NE; ++e) {
    const float4 r4 = reinterpret_cast<const float4*>(rw + (size_t)e * H_DIM)[tid];
    lg[e] = xv0 * r4.x + xv1 * r4.y + xv2 * r4.z + xv3 * r4.w;
  }
#pragma unroll
  for (int o = 32; o > 0; o >>= 1) {
#pragma unroll
    for (int e = 0; e < NE; ++e) lg[e] += __shfl_down(lg[e], o);
  }
  if (ln == 0) {
#pragma unroll
    for (int e = 0; e < NE; ++e) redl[wv][e] = lg[e];
  }
  __syncthreads();
  if (tid == 0) {
    float l[NE];
    float m = -1e30f;
#pragma unroll
    for (int e = 0; e < NE; ++e) {
      l[e] = redl[0][e] + redl[1][e] + redl[2][e] + redl[3][e] + rb[e];
      m = fmaxf(m, l[e]);
    }
    float s = 0.f;
#pragma unroll
    for (int e = 0; e < NE; ++e) { l[e] = expf(l[e] - m); s += l[e]; }
    const float inv = 1.0f / s;
#pragma unroll
    for (int e = 0; e < NE; ++e) {
      const float p = l[e] * inv;
      const u64 key = ((u64)__float_as_uint(p) << 32) | (u32)(0xFFFFFFFFu - (u32)t);
      keys[(size_t)e * T_TOK + t] = key;
    }
  }
  if (do_cvt) {
    const int n4each = NE * FF_DIM * H_DIM / 4;
    const int gstride = gridDim.x * blockDim.x;
    for (int i = blockIdx.x * blockDim.x + tid; i < 2 * n4each; i += gstride) {
      const float* s = (i < n4each) ? w1s : w2s;
      __hip_bfloat16* d = (i < n4each) ? w1d : w2d;
      const int j = (i < n4each) ? i : i - n4each;
      const float4 vv = reinterpret_cast<const float4*>(s)[j];
      ushort4 o;
      o.x = bf16_bits(vv.x); o.y = bf16_bits(vv.y);
      o.z = bf16_bits(vv.z); o.w = bf16_bits(vv.w);
      reinterpret_cast<ushort4*>(d)[j] = o;
    }
  }
}

// ---------------- per-expert top-CAP: 4-pass prob radix + LDS tie-break ----------------
#define EQCAP 7168
__global__ __launch_bounds__(1024) void topk_kernel(
    const u64* __restrict__ keys, int* __restrict__ idxl,
    float* __restrict__ gatel, int* __restrict__ tok_list, int* __restrict__ tok_cnt) {
  const int e = blockIdx.x;
  const int tid = threadIdx.x;
  const int lane = tid & 63;
  const u64* ke = keys + (size_t)e * T_TOK;
  __shared__ int hist[256];
  __shared__ u32 s_pref;
  __shared__ int s_k;
  __shared__ int s_cnt;
  __shared__ int s_eq;
  __shared__ u32 eqlist[EQCAP];

  u32 pref = 0;
  int pbits = 0;
  int kneed = CAP;
  for (int pass = 0; pass < 4; ++pass) {
    if (tid < 256) hist[tid] = 0;
    __syncthreads();
    const int shift = 24 - 8 * pass;
    for (int i = tid; i < T_TOK; i += 1024) {
      const u32 hi = (u32)(ke[i] >> 32);
      const bool ok = (pbits == 0) || ((hi >> (32 - pbits)) == pref);
      const int d = ok ? (int)((hi >> shift) & 255) : -1;
      u64 act = __ballot(ok);
      while (act) {
        const int src = __ffsll((long long)act) - 1;
        const int dl = __shfl(d, src);
        const u64 mb = __ballot(ok && (d == dl));
        if (lane == src) atomicAdd(&hist[dl], (int)__popcll(mb));
        act &= ~mb;
      }
    }
    __syncthreads();
    if (tid == 0) {
      int cum = 0;
      int d = 255;
      for (; d >= 0; --d) {
        cum += hist[d];
        if (cum >= kneed) break;
      }
      s_k = kneed - (cum - hist[d]);
      s_pref = (pref << 8) | (u32)d;
    }
    __syncthreads();
    pref = s_pref;
    kneed = s_k;
    pbits += 8;
    __syncthreads();
  }
  const u32 thrp = pref;
  const float thrp_f = __uint_as_float(thrp);

  if (tid == 0) { s_cnt = 0; s_eq = 0; }
  __syncthreads();
  for (int i = tid; i < T_TOK; i += 1024) {
    const u64 key = ke[i];
    const u32 hi = (u32)(key >> 32);
    if (hi > thrp) {
      const int pos = atomicAdd(&s_cnt, 1);
      if (pos < CAP) {
        const int tok = (int)(0xFFFFFFFFu - (u32)key);
        idxl[e * CAP + pos] = tok;
        gatel[e * CAP + pos] = __uint_as_float(hi);
        const int j = atomicAdd(tok_cnt + tok, 1);
        if (j < NE) tok_list[tok * NE + j] = e * CAP + pos;
      }
    } else if (hi == thrp) {
      const int j = atomicAdd(&s_eq, 1);
      if (j < EQCAP) eqlist[j] = (u32)key;
    }
  }
  __syncthreads();
  const int neq = s_eq;
  if (neq <= EQCAP) {
    u32 prefl = 0;
    int pb = 0;
    int kn = kneed;
    if (neq > kneed) {
      for (int pass = 0; pass < 4; ++pass) {
        if (tid < 256) hist[tid] = 0;
        __syncthreads();
        const int shift = 24 - 8 * pass;
        for (int i = tid; i < neq; i += 1024) {
          const u32 vv = eqlist[i];
          if ((pb == 0) || ((vv >> (32 - pb)) == prefl)) atomicAdd(&hist[(vv >> shift) & 255], 1);
        }
        __syncthreads();
        if (tid == 0) {
          int cum = 0;
          int d = 255;
          for (; d >= 0; --d) {
            cum += hist[d];
            if (cum >= kn) break;
          }
          s_k = kn - (cum - hist[d]);
          s_pref = (prefl << 8) | (u32)d;
        }
        __syncthreads();
        prefl = s_pref;
        kn = s_k;
        pb += 8;
        __syncthreads();
      }
    }
    for (int i = tid; i < neq; i += 1024) {
      const u32 lo = eqlist[i];
      if (neq <= kneed || lo >= prefl) {
        const int pos = atomicAdd(&s_cnt, 1);
        if (pos < CAP) {
          const int tok = (int)(0xFFFFFFFFu - lo);
          idxl[e * CAP + pos] = tok;
          gatel[e * CAP + pos] = thrp_f;
          const int j = atomicAdd(tok_cnt + tok, 1);
          if (j < NE) tok_list[tok * NE + j] = e * CAP + pos;
        }
      }
    }
  } else {
    u64 pref64 = (u64)thrp;
    int pb64 = 32;
    int kn = kneed;
    for (int pass = 4; pass < 8; ++pass) {
      if (tid < 256) hist[tid] = 0;
      __syncthreads();
      const int shift = 56 - 8 * pass;
      for (int i = tid; i < T_TOK; i += 1024) {
        const u64 key = ke[i];
        if ((key >> (64 - pb64)) == pref64) atomicAdd(&hist[(int)((key >> shift) & 255)], 1);
      }
      __syncthreads();
      if (tid == 0) {
        int cum = 0;
        int d = 255;
        for (; d >= 0; --d) {
          cum += hist[d];
          if (cum >= kn) break;
        }
        s_k = kn - (cum - hist[d]);
        s_pref = (u32)d;
      }
      __syncthreads();
      pref64 = (pref64 << 8) | s_pref;
      kn = s_k;
      pb64 += 8;
      __syncthreads();
    }
    for (int i = tid; i < T_TOK; i += 1024) {
      const u64 key = ke[i];
      if ((u32)(key >> 32) == thrp && key >= pref64) {
        const int pos = atomicAdd(&s_cnt, 1);
        if (pos < CAP) {
          const int tok = (int)(0xFFFFFFFFu - (u32)key);
          idxl[e * CAP + pos] = tok;
          gatel[e * CAP + pos] = thrp_f;
          const int j = atomicAdd(tok_cnt + tok, 1);
          if (j < NE) tok_list[tok * NE + j] = e * CAP + pos;
        }
      }
    }
  }
}

// ---------------- fp32 -> bf16 conversion (fallback for EC<8 chunked path) ----------------
__global__ __launch_bounds__(256) void cvt2_kernel(
    const float* __restrict__ s1, __hip_bfloat16* __restrict__ d1,
    const float* __restrict__ s2, __hip_bfloat16* __restrict__ d2, int n4each) {
  int i = blockIdx.x * blockDim.x + threadIdx.x;
  const int stride = gridDim.x * blockDim.x;
  for (; i < 2 * n4each; i += stride) {
    const float* s = (i < n4each) ? s1 : s2;
    __hip_bfloat16* d = (i < n4each) ? d1 : d2;
    const int j = (i < n4each) ? i : i - n4each;
    const float4 v = reinterpret_cast<const float4*>(s)[j];
    ushort4 o;
    o.x = bf16_bits(v.x); o.y = bf16_bits(v.y);
    o.z = bf16_bits(v.z); o.w = bf16_bits(v.w);
    reinterpret_cast<ushort4*>(d)[j] = o;
  }
}

// ---- MFMA GEMM: 256x256 tile, 16 waves (4x4), 64x64/wave via 2x2 of 32x32x16 MFMA ----
// LDS per slot: A [kh:2][row:256][hq:2][e:8] bf16 (16KB) + B same (16KB). K-half-split
// layout makes every 32x32 fragment read a contiguous 1024B bijection -> conflict-free,
// no swizzle. R7's 4-slot ring / counted-vmcnt / 2-phase schedule (phases = k-halves).
// MODE 0: fc1  C = gather(xn, idx) @ w1^T -> bias+gelu -> hmid (bf16)
// MODE 1: fc2  C = hmid @ w2^T            -> bias, gate-weighted bf16 store to ye
template <int MODE>
__global__ __launch_bounds__(1024) void gemm13_kernel(
    const __hip_bfloat16* __restrict__ Asrc, const __hip_bfloat16* __restrict__ Bw,
    const float* __restrict__ bias, const int* __restrict__ idxl,
    const float* __restrict__ gatel, __hip_bfloat16* __restrict__ hmid,
    __hip_bfloat16* __restrict__ ye, int ebase) {
  constexpr int N = (MODE == 0) ? FF_DIM : H_DIM;
  constexpr int K = (MODE == 0) ? H_DIM : FF_DIM;
  constexpr int NBN = N / BN2;
  constexpr int LOG_NBN = (MODE == 0) ? 4 : 2;
  constexpr int BPE = (CAP / BM2) * NBN;
  constexpr int LOG_BPE = (MODE == 0) ? 7 : 5;
  constexpr int NT = K / BK2;

  const int nwg = gridDim.x;
  const int wg0 = blockIdx.x;
  const int wg = (wg0 & 7) * (nwg >> 3) + (wg0 >> 3);
  const int z = wg >> LOG_BPE;
  const int rr = wg & (BPE - 1);
  const int bm = rr >> LOG_NBN;
  const int bn = rr & (NBN - 1);
  const int e = ebase + z;

  const int tid = threadIdx.x;
  const int lane = tid & 63;
  const int w = tid >> 6;
  const int wr = w >> 2, wc = w & 3;  // 4x4 wave grid; wave owns 64x64
  const int l31 = lane & 31;          // MFMA row/col within 32-tile
  const int hi = lane >> 5;           // k-quarter select

  __shared__ char smem[131072];  // 4 slots x 32KB: A @0 (K-split), B @16K (K-split)

  // staging: dest byte tid*16 -> (kh = tid>>9, row = (tid>>1)&255, hq = tid&1)
  const int skh = tid >> 9;
  const int srow = (tid >> 1) & 255;
  const int shq = tid & 1;
  const int selem = skh * 16 + shq * 8;  // element offset within the row's K-slice

  const __hip_bfloat16* asrc;
  if constexpr (MODE == 0) {
    const int t0 = idxl[e * CAP + bm * BM2 + srow];
    asrc = Asrc + (size_t)t0 * H_DIM + selem;
  } else {
    asrc = Asrc + ((size_t)z * CAP + bm * BM2 + srow) * FF_DIM + selem;
  }
  const __hip_bfloat16* bsrc = Bw + (size_t)z * N * K + (size_t)(bn * BN2 + srow) * K + selem;

  // fragment byte offsets: ks*8192 + (base_row + l31)*32 + hi*16  (+16384 for B)
  int aoff[2][2], boff[2][2];  // [mt|nt][ks]
#pragma unroll
  for (int mt = 0; mt < 2; ++mt)
#pragma unroll
    for (int ks = 0; ks < 2; ++ks) {
      aoff[mt][ks] = ks * 8192 + (wr * 64 + mt * 32 + l31) * 32 + hi * 16;
      boff[mt][ks] = 16384 + ks * 8192 + (wc * 64 + mt * 32 + l31) * 32 + hi * 16;
    }

  f32x16 acc00 = {}, acc01 = {}, acc10 = {}, acc11 = {};
  bf16x8 A0k0, A1k0, B0k0, B1k0, A0k1, A1k1, B0k1, B1k1;

#define GLDA(sb, k0) gload_lds16(asrc + (k0), smem + (sb)*32768 + tid * 16)
#define GLDB(sb, k0) gload_lds16(bsrc + (k0), smem + (sb)*32768 + 16384 + tid * 16)

  // prologue: stage tiles 0,1,2
  GLDA(0, 0); GLDB(0, 0);
  GLDA(1, BK2); GLDB(1, BK2);
  GLDA(2, 2 * BK2); GLDB(2, 2 * BK2);
  asm volatile("s_waitcnt vmcnt(4)");  // tile 0 resident
  __builtin_amdgcn_s_barrier();
  __builtin_amdgcn_sched_barrier(0);

  for (int kt = 0; kt < NT; ++kt) {
    const int cur = kt & 3;
    const int kref = (kt + 3 < NT) ? (kt + 3) : (kt + 3 - NT);  // wrapped (harmless)
    const int k0p = kref * BK2;
    const int psl = (kt + 3) & 3;
    const char* base = smem + cur * 32768;

    // ---- pA: ks0 frags first (pinned), then ks1 frags; A-prefetch; vmcnt(3); barrier
    A0k0 = *reinterpret_cast<const bf16x8*>(base + aoff[0][0]);
    A1k0 = *reinterpret_cast<const bf16x8*>(base + aoff[1][0]);
    B0k0 = *reinterpret_cast<const bf16x8*>(base + boff[0][0]);
    B1k0 = *reinterpret_cast<const bf16x8*>(base + boff[1][0]);
    __builtin_amdgcn_sched_barrier(0);  // pin: ks0 reads issue before ks1 reads
    A0k1 = *reinterpret_cast<const bf16x8*>(base + aoff[0][1]);
    A1k1 = *reinterpret_cast<const bf16x8*>(base + aoff[1][1]);
    B0k1 = *reinterpret_cast<const bf16x8*>(base + boff[0][1]);
    B1k1 = *reinterpret_cast<const bf16x8*>(base + boff[1][1]);
    GLDA(psl, k0p);
    asm volatile("s_waitcnt vmcnt(3)");  // tile kt+1 fully resident (induction from prologue)
    __builtin_amdgcn_s_barrier();
    asm volatile("s_waitcnt lgkmcnt(4)");  // ks0 frags ready; ks1 drain under MFMA
    __builtin_amdgcn_sched_barrier(0);
    __builtin_amdgcn_s_setprio(1);
    acc00 = __builtin_amdgcn_mfma_f32_32x32x16_bf16(A0k0, B0k0, acc00, 0, 0, 0);
    acc01 = __builtin_amdgcn_mfma_f32_32x32x16_bf16(A0k0, B1k0, acc01, 0, 0, 0);
    acc10 = __builtin_amdgcn_mfma_f32_32x32x16_bf16(A1k0, B0k0, acc10, 0, 0, 0);
    acc11 = __builtin_amdgcn_mfma_f32_32x32x16_bf16(A1k0, B1k0, acc11, 0, 0, 0);
    __builtin_amdgcn_s_setprio(0);
    __builtin_amdgcn_sched_barrier(0);

    // ---- pB: B-prefetch, drain own reads pre-barrier (slot-reuse soundness), barrier
    GLDB(psl, k0p);
    asm volatile("s_waitcnt lgkmcnt(0)");
    __builtin_amdgcn_sched_barrier(0);
    __builtin_amdgcn_s_barrier();
    __builtin_amdgcn_sched_barrier(0);
    __builtin_amdgcn_s_setprio(1);
    acc00 = __builtin_amdgcn_mfma_f32_32x32x16_bf16(A0k1, B0k1, acc00, 0, 0, 0);
    acc01 = __builtin_amdgcn_mfma_f32_32x32x16_bf16(A0k1, B1k1, acc01, 0, 0, 0);
    acc10 = __builtin_amdgcn_mfma_f32_32x32x16_bf16(A1k1, B0k1, acc10, 0, 0, 0);
    acc11 = __builtin_amdgcn_mfma_f32_32x32x16_bf16(A1k1, B1k1, acc11, 0, 0, 0);
    __builtin_amdgcn_s_setprio(0);
    __builtin_amdgcn_sched_barrier(0);
  }
#undef GLDA
#undef GLDB

  // epilogue: C/D layout (32x32): col = lane&31, row = (r&3) + 8*(r>>2) + 4*(lane>>5)
#define EPI(accv, mt, nt)                                                               \
  do {                                                                                  \
    const int gcol = bn * BN2 + wc * 64 + (nt)*32 + l31;                                \
    const float bb = bias[e * ((MODE == 0) ? FF_DIM : H_DIM) + gcol];                   \
    _Pragma("unroll") for (int r_ = 0; r_ < 16; ++r_) {                                 \
      const int grow = bm * BM2 + wr * 64 + (mt)*32 + (r_ & 3) + 8 * (r_ >> 2) + 4 * hi;\
      if constexpr (MODE == 0) {                                                        \
        const float v_ = accv[r_] + bb;                                                 \
        const float u_ = v_ * (1.5957691216f + 0.0713548162972f * v_ * v_);             \
        const float s_ = 1.0f / (1.0f + __expf(-u_));                                   \
        hmid[((size_t)z * CAP + grow) * FF_DIM + gcol] = __float2bfloat16(v_ * s_);     \
      } else {                                                                          \
        const float gt_ = gatel[e * CAP + grow];                                        \
        ye[((size_t)e * CAP + grow) * H_DIM + gcol] =                                   \
            __float2bfloat16((accv[r_] + bb) * gt_);                                    \
      }                                                                                 \
    }                                                                                   \
  } while (0)

  EPI(acc00, 0, 0);
  EPI(acc01, 0, 1);
  EPI(acc10, 1, 0);
  EPI(acc11, 1, 1);
#undef EPI
}

// ---------------- combine: gather <=8 expert rows per token, sum, normalize ----------------
__global__ __launch_bounds__(256) void combine_kernel(
    const __hip_bfloat16* __restrict__ ye, const float* __restrict__ gatel,
    const int* __restrict__ tok_list, const int* __restrict__ tok_cnt,
    float* __restrict__ out) {
  const int t = blockIdx.x;
  const int tid = threadIdx.x;
  const int cnt = tok_cnt[t];
  float a0 = 0.f, a1 = 0.f, a2 = 0.f, a3 = 0.f, gs = 0.f;
  for (int j = 0; j < cnt && j < NE; ++j) {
    const int ent = tok_list[t * NE + j];
    gs += gatel[ent];
    const ushort4 v = reinterpret_cast<const ushort4*>(ye + (size_t)ent * H_DIM)[tid];
    a0 += bits_f32(v.x);
    a1 += bits_f32(v.y);
    a2 += bits_f32(v.z);
    a3 += bits_f32(v.w);
  }
  const float inv = 1.0f / fmaxf(gs, 1e-9f);
  float4 o;
  o.x = a0 * inv; o.y = a1 * inv; o.z = a2 * inv; o.w = a3 * inv;
  reinterpret_cast<float4*>(out + (size_t)t * H_DIM)[tid] = o;
}

extern "C" void kernel_launch(void* const* d_in, const int* in_sizes, int n_in,
                              void* d_out, int out_size, void* d_ws, size_t ws_size,
                              hipStream_t stream) {
  const float* x = (const float*)d_in[0];
  const float* nw = (const float*)d_in[1];
  const float* rw = (const float*)d_in[2];
  const float* rb = (const float*)d_in[3];
  const float* fc1w = (const float*)d_in[4];
  const float* fc1b = (const float*)d_in[5];
  const float* fc2w = (const float*)d_in[6];
  const float* fc2b = (const float*)d_in[7];
  float* out = (float*)d_out;

  char* ws = (char*)d_ws;
  size_t off = 0;
  auto alloc = [&](size_t b) {
    char* p = ws + off;
    off += (b + 255) & ~(size_t)255;
    return p;
  };
  __hip_bfloat16* xn = (__hip_bfloat16*)alloc((size_t)T_TOK * H_DIM * 2);
  u64* keys = (u64*)alloc((size_t)NE * T_TOK * 8);
  int* idxl = (int*)alloc((size_t)NE * CAP * 4);
  float* gatel = (float*)alloc((size_t)NE * CAP * 4);
  int* tok_list = (int*)alloc((size_t)T_TOK * NE * 4);
  int* tok_cnt = (int*)alloc((size_t)T_TOK * 4);
  __hip_bfloat16* ye = (__hip_bfloat16*)alloc((size_t)NE * CAP * H_DIM * 2);

  int EC = NE;
  while (EC > 1) {
    const size_t per = (size_t)EC * ((size_t)FF_DIM * H_DIM * 2 * 2 + (size_t)CAP * FF_DIM * 2);
    if (off + per + 4096 <= ws_size) break;
    EC >>= 1;
  }
  __hip_bfloat16* w1b = (__hip_bfloat16*)alloc((size_t)EC * FF_DIM * H_DIM * 2);
  __hip_bfloat16* w2b = (__hip_bfloat16*)alloc((size_t)EC * H_DIM * FF_DIM * 2);
  __hip_bfloat16* hmid = (__hip_bfloat16*)alloc((size_t)EC * CAP * FF_DIM * 2);

  const int fused_cvt = (EC == NE) ? 1 : 0;

  router_kernel<<<T_TOK, 256, 0, stream>>>(x, nw, rw, rb, xn, keys, tok_cnt,
                                           fc1w, w1b, fc2w, w2b, fused_cvt);
  topk_kernel<<<NE, 1024, 0, stream>>>(keys, idxl, gatel, tok_list, tok_cnt);

  for (int eb = 0; eb < NE; eb += EC) {
    if (!fused_cvt) {
      const int n4 = EC * FF_DIM * H_DIM / 4;
      cvt2_kernel<<<4096, 256, 0, stream>>>(fc1w + (size_t)eb * FF_DIM * H_DIM, w1b,
                                            fc2w + (size_t)eb * H_DIM * FF_DIM, w2b, n4);
    }
    const int nb1 = EC * (CAP / BM2) * (FF_DIM / BN2);
    gemm13_kernel<0><<<nb1, 1024, 0, stream>>>(xn, w1b, fc1b, idxl, gatel, hmid, ye, eb);
    const int nb2 = EC * (CAP / BM2) * (H_DIM / BN2);
    gemm13_kernel<1><<<nb2, 1024, 0, stream>>>(hmid, w2b, fc2b, idxl, gatel, hmid, ye, eb);
  }
  combine_kernel<<<T_TOK, 256, 0, stream>>>(ye, gatel, tok_list, tok_cnt, out);
}

// Round 15
// 540.741 us; speedup vs baseline: 1.0474x; 1.0474x over previous
//
#include <hip/hip_runtime.h>
#include <hip/hip_bf16.h>

#define T_TOK 16384
#define H_DIM 1024
#define FF_DIM 4096
#define NE 8
#define CAP 2048
#define EPS_F 1e-5f

#define BM2 256
#define BN2 256
#define BK2 32

typedef __attribute__((ext_vector_type(4))) float f32x4;
typedef __attribute__((ext_vector_type(16))) float f32x16;
typedef __attribute__((ext_vector_type(8))) short bf16x8;
typedef unsigned long long u64;
typedef unsigned int u32;

__device__ inline void gload_lds16(const void* g, void* l) {
  __builtin_amdgcn_global_load_lds(
      (const __attribute__((address_space(1))) unsigned int*)g,
      (__attribute__((address_space(3))) unsigned int*)l, 16, 0, 0);
}

__device__ inline unsigned short bf16_bits(float f) {
  __hip_bfloat16 h = __float2bfloat16(f);
  unsigned short u;
  __builtin_memcpy(&u, &h, 2);
  return u;
}

__device__ inline float bits_f32(unsigned short u) {
  const u32 x = ((u32)u) << 16;
  float f;
  __builtin_memcpy(&f, &x, 4);
  return f;
}

// ---- router: RMSNorm + logits + softmax + keys; zeroes tok_cnt; (EC=8) converts weights
__global__ __launch_bounds__(256) void router_kernel(
    const float* __restrict__ x, const float* __restrict__ nw,
    const float* __restrict__ rw, const float* __restrict__ rb,
    __hip_bfloat16* __restrict__ xn, u64* __restrict__ keys,
    int* __restrict__ tok_cnt,
    const float* __restrict__ w1s, __hip_bfloat16* __restrict__ w1d,
    const float* __restrict__ w2s, __hip_bfloat16* __restrict__ w2d, int do_cvt) {
  const int t = blockIdx.x;
  const int tid = threadIdx.x;
  if (tid == 0) tok_cnt[t] = 0;
  const float4 v = reinterpret_cast<const float4*>(x + (size_t)t * H_DIM)[tid];
  float ss = v.x * v.x + v.y * v.y + v.z * v.z + v.w * v.w;
#pragma unroll
  for (int o = 32; o > 0; o >>= 1) ss += __shfl_down(ss, o);
  __shared__ float red[4];
  __shared__ float redl[4][NE];
  const int wv = tid >> 6, ln = tid & 63;
  if (ln == 0) red[wv] = ss;
  __syncthreads();
  const float tot = red[0] + red[1] + red[2] + red[3];
  const float scale = rsqrtf(tot * (1.0f / H_DIM) + EPS_F);
  const float4 w4 = reinterpret_cast<const float4*>(nw)[tid];
  float xv0 = v.x * scale * w4.x, xv1 = v.y * scale * w4.y;
  float xv2 = v.z * scale * w4.z, xv3 = v.w * scale * w4.w;
  ushort4 u4;
  u4.x = bf16_bits(xv0); u4.y = bf16_bits(xv1);
  u4.z = bf16_bits(xv2); u4.w = bf16_bits(xv3);
  reinterpret_cast<ushort4*>(xn + (size_t)t * H_DIM)[tid] = u4;
  float lg[NE];
#pragma unroll
  for (int e = 0; e < NE; ++e) {
    const float4 r4 = reinterpret_cast<const float4*>(rw + (size_t)e * H_DIM)[tid];
    lg[e] = xv0 * r4.x + xv1 * r4.y + xv2 * r4.z + xv3 * r4.w;
  }
#pragma unroll
  for (int o = 32; o > 0; o >>= 1) {
#pragma unroll
    for (int e = 0; e < NE; ++e) lg[e] += __shfl_down(lg[e], o);
  }
  if (ln == 0) {
#pragma unroll
    for (int e = 0; e < NE; ++e) redl[wv][e] = lg[e];
  }
  __syncthreads();
  if (tid == 0) {
    float l[NE];
    float m = -1e30f;
#pragma unroll
    for (int e = 0; e < NE; ++e) {
      l[e] = redl[0][e] + redl[1][e] + redl[2][e] + redl[3][e] + rb[e];
      m = fmaxf(m, l[e]);
    }
    float s = 0.f;
#pragma unroll
    for (int e = 0; e < NE; ++e) { l[e] = expf(l[e] - m); s += l[e]; }
    const float inv = 1.0f / s;
#pragma unroll
    for (int e = 0; e < NE; ++e) {
      const float p = l[e] * inv;
      const u64 key = ((u64)__float_as_uint(p) << 32) | (u32)(0xFFFFFFFFu - (u32)t);
      keys[(size_t)e * T_TOK + t] = key;
    }
  }
  if (do_cvt) {
    const int n4each = NE * FF_DIM * H_DIM / 4;
    const int gstride = gridDim.x * blockDim.x;
    for (int i = blockIdx.x * blockDim.x + tid; i < 2 * n4each; i += gstride) {
      const float* s = (i < n4each) ? w1s : w2s;
      __hip_bfloat16* d = (i < n4each) ? w1d : w2d;
      const int j = (i < n4each) ? i : i - n4each;
      const float4 vv = reinterpret_cast<const float4*>(s)[j];
      ushort4 o;
      o.x = bf16_bits(vv.x); o.y = bf16_bits(vv.y);
      o.z = bf16_bits(vv.z); o.w = bf16_bits(vv.w);
      reinterpret_cast<ushort4*>(d)[j] = o;
    }
  }
}

// ---------------- per-expert top-CAP: 4-pass prob radix + LDS tie-break ----------------
#define EQCAP 7168
__global__ __launch_bounds__(1024) void topk_kernel(
    const u64* __restrict__ keys, int* __restrict__ idxl,
    float* __restrict__ gatel, int* __restrict__ tok_list, int* __restrict__ tok_cnt) {
  const int e = blockIdx.x;
  const int tid = threadIdx.x;
  const int lane = tid & 63;
  const u64* ke = keys + (size_t)e * T_TOK;
  __shared__ int hist[256];
  __shared__ u32 s_pref;
  __shared__ int s_k;
  __shared__ int s_cnt;
  __shared__ int s_eq;
  __shared__ u32 eqlist[EQCAP];

  u32 pref = 0;
  int pbits = 0;
  int kneed = CAP;
  for (int pass = 0; pass < 4; ++pass) {
    if (tid < 256) hist[tid] = 0;
    __syncthreads();
    const int shift = 24 - 8 * pass;
    for (int i = tid; i < T_TOK; i += 1024) {
      const u32 hi = (u32)(ke[i] >> 32);
      const bool ok = (pbits == 0) || ((hi >> (32 - pbits)) == pref);
      const int d = ok ? (int)((hi >> shift) & 255) : -1;
      u64 act = __ballot(ok);
      while (act) {
        const int src = __ffsll((long long)act) - 1;
        const int dl = __shfl(d, src);
        const u64 mb = __ballot(ok && (d == dl));
        if (lane == src) atomicAdd(&hist[dl], (int)__popcll(mb));
        act &= ~mb;
      }
    }
    __syncthreads();
    if (tid == 0) {
      int cum = 0;
      int d = 255;
      for (; d >= 0; --d) {
        cum += hist[d];
        if (cum >= kneed) break;
      }
      s_k = kneed - (cum - hist[d]);
      s_pref = (pref << 8) | (u32)d;
    }
    __syncthreads();
    pref = s_pref;
    kneed = s_k;
    pbits += 8;
    __syncthreads();
  }
  const u32 thrp = pref;
  const float thrp_f = __uint_as_float(thrp);

  if (tid == 0) { s_cnt = 0; s_eq = 0; }
  __syncthreads();
  for (int i = tid; i < T_TOK; i += 1024) {
    const u64 key = ke[i];
    const u32 hi = (u32)(key >> 32);
    if (hi > thrp) {
      const int pos = atomicAdd(&s_cnt, 1);
      if (pos < CAP) {
        const int tok = (int)(0xFFFFFFFFu - (u32)key);
        idxl[e * CAP + pos] = tok;
        gatel[e * CAP + pos] = __uint_as_float(hi);
        const int j = atomicAdd(tok_cnt + tok, 1);
        if (j < NE) tok_list[tok * NE + j] = e * CAP + pos;
      }
    } else if (hi == thrp) {
      const int j = atomicAdd(&s_eq, 1);
      if (j < EQCAP) eqlist[j] = (u32)key;
    }
  }
  __syncthreads();
  const int neq = s_eq;
  if (neq <= EQCAP) {
    u32 prefl = 0;
    int pb = 0;
    int kn = kneed;
    if (neq > kneed) {
      for (int pass = 0; pass < 4; ++pass) {
        if (tid < 256) hist[tid] = 0;
        __syncthreads();
        const int shift = 24 - 8 * pass;
        for (int i = tid; i < neq; i += 1024) {
          const u32 vv = eqlist[i];
          if ((pb == 0) || ((vv >> (32 - pb)) == prefl)) atomicAdd(&hist[(vv >> shift) & 255], 1);
        }
        __syncthreads();
        if (tid == 0) {
          int cum = 0;
          int d = 255;
          for (; d >= 0; --d) {
            cum += hist[d];
            if (cum >= kn) break;
          }
          s_k = kn - (cum - hist[d]);
          s_pref = (prefl << 8) | (u32)d;
        }
        __syncthreads();
        prefl = s_pref;
        kn = s_k;
        pb += 8;
        __syncthreads();
      }
    }
    for (int i = tid; i < neq; i += 1024) {
      const u32 lo = eqlist[i];
      if (neq <= kneed || lo >= prefl) {
        const int pos = atomicAdd(&s_cnt, 1);
        if (pos < CAP) {
          const int tok = (int)(0xFFFFFFFFu - lo);
          idxl[e * CAP + pos] = tok;
          gatel[e * CAP + pos] = thrp_f;
          const int j = atomicAdd(tok_cnt + tok, 1);
          if (j < NE) tok_list[tok * NE + j] = e * CAP + pos;
        }
      }
    }
  } else {
    u64 pref64 = (u64)thrp;
    int pb64 = 32;
    int kn = kneed;
    for (int pass = 4; pass < 8; ++pass) {
      if (tid < 256) hist[tid] = 0;
      __syncthreads();
      const int shift = 56 - 8 * pass;
      for (int i = tid; i < T_TOK; i += 1024) {
        const u64 key = ke[i];
        if ((key >> (64 - pb64)) == pref64) atomicAdd(&hist[(int)((key >> shift) & 255)], 1);
      }
      __syncthreads();
      if (tid == 0) {
        int cum = 0;
        int d = 255;
        for (; d >= 0; --d) {
          cum += hist[d];
          if (cum >= kn) break;
        }
        s_k = kn - (cum - hist[d]);
        s_pref = (u32)d;
      }
      __syncthreads();
      pref64 = (pref64 << 8) | s_pref;
      kn = s_k;
      pb64 += 8;
      __syncthreads();
    }
    for (int i = tid; i < T_TOK; i += 1024) {
      const u64 key = ke[i];
      if ((u32)(key >> 32) == thrp && key >= pref64) {
        const int pos = atomicAdd(&s_cnt, 1);
        if (pos < CAP) {
          const int tok = (int)(0xFFFFFFFFu - (u32)key);
          idxl[e * CAP + pos] = tok;
          gatel[e * CAP + pos] = thrp_f;
          const int j = atomicAdd(tok_cnt + tok, 1);
          if (j < NE) tok_list[tok * NE + j] = e * CAP + pos;
        }
      }
    }
  }
}

// ---------------- fp32 -> bf16 conversion (fallback for EC<8 chunked path) ----------------
__global__ __launch_bounds__(256) void cvt2_kernel(
    const float* __restrict__ s1, __hip_bfloat16* __restrict__ d1,
    const float* __restrict__ s2, __hip_bfloat16* __restrict__ d2, int n4each) {
  int i = blockIdx.x * blockDim.x + threadIdx.x;
  const int stride = gridDim.x * blockDim.x;
  for (; i < 2 * n4each; i += stride) {
    const float* s = (i < n4each) ? s1 : s2;
    __hip_bfloat16* d = (i < n4each) ? d1 : d2;
    const int j = (i < n4each) ? i : i - n4each;
    const float4 v = reinterpret_cast<const float4*>(s)[j];
    ushort4 o;
    o.x = bf16_bits(v.x); o.y = bf16_bits(v.y);
    o.z = bf16_bits(v.z); o.w = bf16_bits(v.w);
    reinterpret_cast<ushort4*>(d)[j] = o;
  }
}

// ---- MFMA GEMM: 256x256 tile, 16 waves (4x4), 64x64/wave via 2x2 of 32x32x16 MFMA ----
// LDS layout + staging + 4-slot ring + schedule = gemm7 (R7, measured 0 conflicts) verbatim.
// Only the fragment addressing (32-row form of the same swizzle) and MFMA shape change:
// granule (row, kg) at slot kg ^ ((row>>1)&3); 16-lane read group covers all 8 slot
// combos -> 2-way (free). 8 MFMA/K-tile instead of 16.
// MODE 0: fc1  C = gather(xn, idx) @ w1^T -> bias+gelu -> hmid (bf16)
// MODE 1: fc2  C = hmid @ w2^T            -> bias, gate-weighted bf16 store to ye
template <int MODE>
__global__ __launch_bounds__(1024) void gemm14_kernel(
    const __hip_bfloat16* __restrict__ Asrc, const __hip_bfloat16* __restrict__ Bw,
    const float* __restrict__ bias, const int* __restrict__ idxl,
    const float* __restrict__ gatel, __hip_bfloat16* __restrict__ hmid,
    __hip_bfloat16* __restrict__ ye, int ebase) {
  constexpr int N = (MODE == 0) ? FF_DIM : H_DIM;
  constexpr int K = (MODE == 0) ? H_DIM : FF_DIM;
  constexpr int NBN = N / BN2;
  constexpr int LOG_NBN = (MODE == 0) ? 4 : 2;
  constexpr int BPE = (CAP / BM2) * NBN;
  constexpr int LOG_BPE = (MODE == 0) ? 7 : 5;
  constexpr int NT = K / BK2;

  const int nwg = gridDim.x;
  const int wg0 = blockIdx.x;
  const int wg = (wg0 & 7) * (nwg >> 3) + (wg0 >> 3);
  const int z = wg >> LOG_BPE;
  const int rr = wg & (BPE - 1);
  const int bm = rr >> LOG_NBN;
  const int bn = rr & (NBN - 1);
  const int e = ebase + z;

  const int tid = threadIdx.x;
  const int lane = tid & 63;
  const int w = tid >> 6;
  const int wr = w >> 2, wc = w & 3;  // 4x4 wave grid; wave owns 64x64
  const int l31 = lane & 31;
  const int hi = lane >> 5;

  __shared__ char smem[131072];  // 4 slots x 32KB: A@0 (256 rows x 64B), B@16K

  // staging identical to gemm7: row = tid>>2, granule = tid&3, swizzled source
  const int srow = tid >> 2;
  const int sg = tid & 3;
  const int skoff = (sg ^ ((srow >> 1) & 3)) * 8;

  const __hip_bfloat16* asrc;
  if constexpr (MODE == 0) {
    const int t0 = idxl[e * CAP + bm * BM2 + srow];
    asrc = Asrc + (size_t)t0 * H_DIM + skoff;
  } else {
    asrc = Asrc + ((size_t)z * CAP + bm * BM2 + srow) * FF_DIM + skoff;
  }
  const __hip_bfloat16* bsrc = Bw + (size_t)z * N * K + (size_t)(bn * BN2 + srow) * K + skoff;

  // fragment offsets: row = base + l31 (base mult of 32 -> swizzle uses l31 only)
  const int sw = (l31 >> 1) & 3;
  int aoff[2][2], boff[2][2];  // [mt|nt][ks], granule kg = ks*2 + hi
#pragma unroll
  for (int mt = 0; mt < 2; ++mt)
#pragma unroll
    for (int ks = 0; ks < 2; ++ks) {
      const int kg = ks * 2 + hi;
      aoff[mt][ks] = (wr * 64 + mt * 32 + l31) * 64 + ((kg ^ sw) << 4);
      boff[mt][ks] = 16384 + (wc * 64 + mt * 32 + l31) * 64 + ((kg ^ sw) << 4);
    }

  f32x16 acc00 = {}, acc01 = {}, acc10 = {}, acc11 = {};
  bf16x8 A0k0, A1k0, B0k0, B1k0, A0k1, A1k1, B0k1, B1k1;

#define GLDA(sb, k0) gload_lds16(asrc + (k0), smem + (sb)*32768 + tid * 16)
#define GLDB(sb, k0) gload_lds16(bsrc + (k0), smem + (sb)*32768 + 16384 + tid * 16)

  // prologue: stage tiles 0,1,2 (gemm7 verbatim)
  GLDA(0, 0); GLDB(0, 0);
  GLDA(1, BK2); GLDB(1, BK2);
  GLDA(2, 2 * BK2); GLDB(2, 2 * BK2);
  asm volatile("s_waitcnt vmcnt(4)");  // tile 0 resident
  __builtin_amdgcn_s_barrier();
  __builtin_amdgcn_sched_barrier(0);

  for (int kt = 0; kt < NT; ++kt) {
    const int cur = kt & 3;
    const int kref = (kt + 3 < NT) ? (kt + 3) : (kt + 3 - NT);  // wrapped (harmless)
    const int k0p = kref * BK2;
    const int psl = (kt + 3) & 3;
    const char* base = smem + cur * 32768;

    // ---- pA: ks0 frags first (pinned), ks1 after; A-prefetch; vmcnt(3); barrier
    A0k0 = *reinterpret_cast<const bf16x8*>(base + aoff[0][0]);
    A1k0 = *reinterpret_cast<const bf16x8*>(base + aoff[1][0]);
    B0k0 = *reinterpret_cast<const bf16x8*>(base + boff[0][0]);
    B1k0 = *reinterpret_cast<const bf16x8*>(base + boff[1][0]);
    __builtin_amdgcn_sched_barrier(0);  // pin: ks0 reads issue before ks1
    A0k1 = *reinterpret_cast<const bf16x8*>(base + aoff[0][1]);
    A1k1 = *reinterpret_cast<const bf16x8*>(base + aoff[1][1]);
    B0k1 = *reinterpret_cast<const bf16x8*>(base + boff[0][1]);
    B1k1 = *reinterpret_cast<const bf16x8*>(base + boff[1][1]);
    GLDA(psl, k0p);
    asm volatile("s_waitcnt vmcnt(3)");  // tile kt+1 fully resident (induction)
    __builtin_amdgcn_s_barrier();
    asm volatile("s_waitcnt lgkmcnt(4)");  // ks0 frags ready; ks1 drain under MFMA
    __builtin_amdgcn_sched_barrier(0);
    __builtin_amdgcn_s_setprio(1);
    acc00 = __builtin_amdgcn_mfma_f32_32x32x16_bf16(A0k0, B0k0, acc00, 0, 0, 0);
    acc01 = __builtin_amdgcn_mfma_f32_32x32x16_bf16(A0k0, B1k0, acc01, 0, 0, 0);
    acc10 = __builtin_amdgcn_mfma_f32_32x32x16_bf16(A1k0, B0k0, acc10, 0, 0, 0);
    acc11 = __builtin_amdgcn_mfma_f32_32x32x16_bf16(A1k0, B1k0, acc11, 0, 0, 0);
    __builtin_amdgcn_s_setprio(0);
    __builtin_amdgcn_sched_barrier(0);

    // ---- pB: B-prefetch, drain own reads pre-barrier (slot-reuse soundness), barrier
    GLDB(psl, k0p);
    asm volatile("s_waitcnt lgkmcnt(0)");
    __builtin_amdgcn_sched_barrier(0);
    __builtin_amdgcn_s_barrier();
    __builtin_amdgcn_sched_barrier(0);
    __builtin_amdgcn_s_setprio(1);
    acc00 = __builtin_amdgcn_mfma_f32_32x32x16_bf16(A0k1, B0k1, acc00, 0, 0, 0);
    acc01 = __builtin_amdgcn_mfma_f32_32x32x16_bf16(A0k1, B1k1, acc01, 0, 0, 0);
    acc10 = __builtin_amdgcn_mfma_f32_32x32x16_bf16(A1k1, B0k1, acc10, 0, 0, 0);
    acc11 = __builtin_amdgcn_mfma_f32_32x32x16_bf16(A1k1, B1k1, acc11, 0, 0, 0);
    __builtin_amdgcn_s_setprio(0);
    __builtin_amdgcn_sched_barrier(0);
  }
#undef GLDA
#undef GLDB

  // epilogue (R14-verified): col = lane&31, row = (r&3) + 8*(r>>2) + 4*hi
#define EPI(accv, mt, nt)                                                               \
  do {                                                                                  \
    const int gcol = bn * BN2 + wc * 64 + (nt)*32 + l31;                                \
    const float bb = bias[e * ((MODE == 0) ? FF_DIM : H_DIM) + gcol];                   \
    _Pragma("unroll") for (int r_ = 0; r_ < 16; ++r_) {                                 \
      const int grow = bm * BM2 + wr * 64 + (mt)*32 + (r_ & 3) + 8 * (r_ >> 2) + 4 * hi;\
      if constexpr (MODE == 0) {                                                        \
        const float v_ = accv[r_] + bb;                                                 \
        const float u_ = v_ * (1.5957691216f + 0.0713548162972f * v_ * v_);             \
        const float s_ = 1.0f / (1.0f + __expf(-u_));                                   \
        hmid[((size_t)z * CAP + grow) * FF_DIM + gcol] = __float2bfloat16(v_ * s_);     \
      } else {                                                                          \
        const float gt_ = gatel[e * CAP + grow];                                        \
        ye[((size_t)e * CAP + grow) * H_DIM + gcol] =                                   \
            __float2bfloat16((accv[r_] + bb) * gt_);                                    \
      }                                                                                 \
    }                                                                                   \
  } while (0)

  EPI(acc00, 0, 0);
  EPI(acc01, 0, 1);
  EPI(acc10, 1, 0);
  EPI(acc11, 1, 1);
#undef EPI
}

// ---------------- combine: gather <=8 expert rows per token, sum, normalize ----------------
__global__ __launch_bounds__(256) void combine_kernel(
    const __hip_bfloat16* __restrict__ ye, const float* __restrict__ gatel,
    const int* __restrict__ tok_list, const int* __restrict__ tok_cnt,
    float* __restrict__ out) {
  const int t = blockIdx.x;
  const int tid = threadIdx.x;
  const int cnt = tok_cnt[t];
  float a0 = 0.f, a1 = 0.f, a2 = 0.f, a3 = 0.f, gs = 0.f;
  for (int j = 0; j < cnt && j < NE; ++j) {
    const int ent = tok_list[t * NE + j];
    gs += gatel[ent];
    const ushort4 v = reinterpret_cast<const ushort4*>(ye + (size_t)ent * H_DIM)[tid];
    a0 += bits_f32(v.x);
    a1 += bits_f32(v.y);
    a2 += bits_f32(v.z);
    a3 += bits_f32(v.w);
  }
  const float inv = 1.0f / fmaxf(gs, 1e-9f);
  float4 o;
  o.x = a0 * inv; o.y = a1 * inv; o.z = a2 * inv; o.w = a3 * inv;
  reinterpret_cast<float4*>(out + (size_t)t * H_DIM)[tid] = o;
}

extern "C" void kernel_launch(void* const* d_in, const int* in_sizes, int n_in,
                              void* d_out, int out_size, void* d_ws, size_t ws_size,
                              hipStream_t stream) {
  const float* x = (const float*)d_in[0];
  const float* nw = (const float*)d_in[1];
  const float* rw = (const float*)d_in[2];
  const float* rb = (const float*)d_in[3];
  const float* fc1w = (const float*)d_in[4];
  const float* fc1b = (const float*)d_in[5];
  const float* fc2w = (const float*)d_in[6];
  const float* fc2b = (const float*)d_in[7];
  float* out = (float*)d_out;

  char* ws = (char*)d_ws;
  size_t off = 0;
  auto alloc = [&](size_t b) {
    char* p = ws + off;
    off += (b + 255) & ~(size_t)255;
    return p;
  };
  __hip_bfloat16* xn = (__hip_bfloat16*)alloc((size_t)T_TOK * H_DIM * 2);
  u64* keys = (u64*)alloc((size_t)NE * T_TOK * 8);
  int* idxl = (int*)alloc((size_t)NE * CAP * 4);
  float* gatel = (float*)alloc((size_t)NE * CAP * 4);
  int* tok_list = (int*)alloc((size_t)T_TOK * NE * 4);
  int* tok_cnt = (int*)alloc((size_t)T_TOK * 4);
  __hip_bfloat16* ye = (__hip_bfloat16*)alloc((size_t)NE * CAP * H_DIM * 2);

  int EC = NE;
  while (EC > 1) {
    const size_t per = (size_t)EC * ((size_t)FF_DIM * H_DIM * 2 * 2 + (size_t)CAP * FF_DIM * 2);
    if (off + per + 4096 <= ws_size) break;
    EC >>= 1;
  }
  __hip_bfloat16* w1b = (__hip_bfloat16*)alloc((size_t)EC * FF_DIM * H_DIM * 2);
  __hip_bfloat16* w2b = (__hip_bfloat16*)alloc((size_t)EC * H_DIM * FF_DIM * 2);
  __hip_bfloat16* hmid = (__hip_bfloat16*)alloc((size_t)EC * CAP * FF_DIM * 2);

  const int fused_cvt = (EC == NE) ? 1 : 0;

  router_kernel<<<T_TOK, 256, 0, stream>>>(x, nw, rw, rb, xn, keys, tok_cnt,
                                           fc1w, w1b, fc2w, w2b, fused_cvt);
  topk_kernel<<<NE, 1024, 0, stream>>>(keys, idxl, gatel, tok_list, tok_cnt);

  for (int eb = 0; eb < NE; eb += EC) {
    if (!fused_cvt) {
      const int n4 = EC * FF_DIM * H_DIM / 4;
      cvt2_kernel<<<4096, 256, 0, stream>>>(fc1w + (size_t)eb * FF_DIM * H_DIM, w1b,
                                            fc2w + (size_t)eb * H_DIM * FF_DIM, w2b, n4);
    }
    const int nb1 = EC * (CAP / BM2) * (FF_DIM / BN2);
    gemm14_kernel<0><<<nb1, 1024, 0, stream>>>(xn, w1b, fc1b, idxl, gatel, hmid, ye, eb);
    const int nb2 = EC * (CAP / BM2) * (H_DIM / BN2);
    gemm14_kernel<1><<<nb2, 1024, 0, stream>>>(hmid, w2b, fc2b, idxl, gatel, hmid, ye, eb);
  }
  combine_kernel<<<T_TOK, 256, 0, stream>>>(ye, gatel, tok_list, tok_cnt, out);
}

// Round 16
// 504.073 us; speedup vs baseline: 1.1236x; 1.0727x over previous
//
#include <hip/hip_runtime.h>
#include <hip/hip_bf16.h>

#define T_TOK 16384
#define H_DIM 1024
#define FF_DIM 4096
#define NE 8
#define CAP 2048
#define EPS_F 1e-5f

#define BM2 256
#define BN2 256
#define BK2 32

typedef __attribute__((ext_vector_type(4))) float f32x4;
typedef __attribute__((ext_vector_type(8))) short bf16x8;
typedef unsigned long long u64;
typedef unsigned int u32;

__device__ inline void gload_lds16(const void* g, void* l) {
  __builtin_amdgcn_global_load_lds(
      (const __attribute__((address_space(1))) unsigned int*)g,
      (__attribute__((address_space(3))) unsigned int*)l, 16, 0, 0);
}

__device__ inline unsigned short bf16_bits(float f) {
  __hip_bfloat16 h = __float2bfloat16(f);
  unsigned short u;
  __builtin_memcpy(&u, &h, 2);
  return u;
}

__device__ inline float bits_f32(unsigned short u) {
  const u32 x = ((u32)u) << 16;
  float f;
  __builtin_memcpy(&f, &x, 4);
  return f;
}

// ---- router: RMSNorm + logits + softmax + keys; zeroes tok_cnt; (EC=8) converts weights
__global__ __launch_bounds__(256) void router_kernel(
    const float* __restrict__ x, const float* __restrict__ nw,
    const float* __restrict__ rw, const float* __restrict__ rb,
    __hip_bfloat16* __restrict__ xn, u64* __restrict__ keys,
    int* __restrict__ tok_cnt,
    const float* __restrict__ w1s, __hip_bfloat16* __restrict__ w1d,
    const float* __restrict__ w2s, __hip_bfloat16* __restrict__ w2d, int do_cvt) {
  const int t = blockIdx.x;
  const int tid = threadIdx.x;
  if (tid == 0) tok_cnt[t] = 0;
  const float4 v = reinterpret_cast<const float4*>(x + (size_t)t * H_DIM)[tid];
  float ss = v.x * v.x + v.y * v.y + v.z * v.z + v.w * v.w;
#pragma unroll
  for (int o = 32; o > 0; o >>= 1) ss += __shfl_down(ss, o);
  __shared__ float red[4];
  __shared__ float redl[4][NE];
  const int wv = tid >> 6, ln = tid & 63;
  if (ln == 0) red[wv] = ss;
  __syncthreads();
  const float tot = red[0] + red[1] + red[2] + red[3];
  const float scale = rsqrtf(tot * (1.0f / H_DIM) + EPS_F);
  const float4 w4 = reinterpret_cast<const float4*>(nw)[tid];
  float xv0 = v.x * scale * w4.x, xv1 = v.y * scale * w4.y;
  float xv2 = v.z * scale * w4.z, xv3 = v.w * scale * w4.w;
  ushort4 u4;
  u4.x = bf16_bits(xv0); u4.y = bf16_bits(xv1);
  u4.z = bf16_bits(xv2); u4.w = bf16_bits(xv3);
  reinterpret_cast<ushort4*>(xn + (size_t)t * H_DIM)[tid] = u4;
  float lg[NE];
#pragma unroll
  for (int e = 0; e < NE; ++e) {
    const float4 r4 = reinterpret_cast<const float4*>(rw + (size_t)e * H_DIM)[tid];
    lg[e] = xv0 * r4.x + xv1 * r4.y + xv2 * r4.z + xv3 * r4.w;
  }
#pragma unroll
  for (int o = 32; o > 0; o >>= 1) {
#pragma unroll
    for (int e = 0; e < NE; ++e) lg[e] += __shfl_down(lg[e], o);
  }
  if (ln == 0) {
#pragma unroll
    for (int e = 0; e < NE; ++e) redl[wv][e] = lg[e];
  }
  __syncthreads();
  if (tid == 0) {
    float l[NE];
    float m = -1e30f;
#pragma unroll
    for (int e = 0; e < NE; ++e) {
      l[e] = redl[0][e] + redl[1][e] + redl[2][e] + redl[3][e] + rb[e];
      m = fmaxf(m, l[e]);
    }
    float s = 0.f;
#pragma unroll
    for (int e = 0; e < NE; ++e) { l[e] = expf(l[e] - m); s += l[e]; }
    const float inv = 1.0f / s;
#pragma unroll
    for (int e = 0; e < NE; ++e) {
      const float p = l[e] * inv;
      const u64 key = ((u64)__float_as_uint(p) << 32) | (u32)(0xFFFFFFFFu - (u32)t);
      keys[(size_t)e * T_TOK + t] = key;
    }
  }
  // fused weight conversion (full-weights path): 2 tensors x 8.39M float4 each
  if (do_cvt) {
    const int n4each = NE * FF_DIM * H_DIM / 4;
    const int gstride = gridDim.x * blockDim.x;
    for (int i = blockIdx.x * blockDim.x + tid; i < 2 * n4each; i += gstride) {
      const float* s = (i < n4each) ? w1s : w2s;
      __hip_bfloat16* d = (i < n4each) ? w1d : w2d;
      const int j = (i < n4each) ? i : i - n4each;
      const float4 vv = reinterpret_cast<const float4*>(s)[j];
      ushort4 o;
      o.x = bf16_bits(vv.x); o.y = bf16_bits(vv.y);
      o.z = bf16_bits(vv.z); o.w = bf16_bits(vv.w);
      reinterpret_cast<ushort4*>(d)[j] = o;
    }
  }
}

// ---------------- per-expert top-CAP: 4-pass prob radix + LDS tie-break ----------------
#define EQCAP 7168
__global__ __launch_bounds__(1024) void topk_kernel(
    const u64* __restrict__ keys, int* __restrict__ idxl,
    float* __restrict__ gatel, int* __restrict__ tok_list, int* __restrict__ tok_cnt) {
  const int e = blockIdx.x;
  const int tid = threadIdx.x;
  const int lane = tid & 63;
  const u64* ke = keys + (size_t)e * T_TOK;
  __shared__ int hist[256];
  __shared__ u32 s_pref;
  __shared__ int s_k;
  __shared__ int s_cnt;
  __shared__ int s_eq;
  __shared__ u32 eqlist[EQCAP];

  u32 pref = 0;
  int pbits = 0;
  int kneed = CAP;
  for (int pass = 0; pass < 4; ++pass) {
    if (tid < 256) hist[tid] = 0;
    __syncthreads();
    const int shift = 24 - 8 * pass;
    for (int i = tid; i < T_TOK; i += 1024) {
      const u32 hi = (u32)(ke[i] >> 32);
      const bool ok = (pbits == 0) || ((hi >> (32 - pbits)) == pref);
      const int d = ok ? (int)((hi >> shift) & 255) : -1;
      u64 act = __ballot(ok);
      while (act) {
        const int src = __ffsll((long long)act) - 1;
        const int dl = __shfl(d, src);
        const u64 mb = __ballot(ok && (d == dl));
        if (lane == src) atomicAdd(&hist[dl], (int)__popcll(mb));
        act &= ~mb;
      }
    }
    __syncthreads();
    if (tid == 0) {
      int cum = 0;
      int d = 255;
      for (; d >= 0; --d) {
        cum += hist[d];
        if (cum >= kneed) break;
      }
      s_k = kneed - (cum - hist[d]);
      s_pref = (pref << 8) | (u32)d;
    }
    __syncthreads();
    pref = s_pref;
    kneed = s_k;
    pbits += 8;
    __syncthreads();
  }
  const u32 thrp = pref;
  const float thrp_f = __uint_as_float(thrp);

  if (tid == 0) { s_cnt = 0; s_eq = 0; }
  __syncthreads();
  for (int i = tid; i < T_TOK; i += 1024) {
    const u64 key = ke[i];
    const u32 hi = (u32)(key >> 32);
    if (hi > thrp) {
      const int pos = atomicAdd(&s_cnt, 1);
      if (pos < CAP) {
        const int tok = (int)(0xFFFFFFFFu - (u32)key);
        idxl[e * CAP + pos] = tok;
        gatel[e * CAP + pos] = __uint_as_float(hi);
        const int j = atomicAdd(tok_cnt + tok, 1);
        if (j < NE) tok_list[tok * NE + j] = e * CAP + pos;
      }
    } else if (hi == thrp) {
      const int j = atomicAdd(&s_eq, 1);
      if (j < EQCAP) eqlist[j] = (u32)key;
    }
  }
  __syncthreads();
  const int neq = s_eq;
  if (neq <= EQCAP) {
    u32 prefl = 0;
    int pb = 0;
    int kn = kneed;
    if (neq > kneed) {
      for (int pass = 0; pass < 4; ++pass) {
        if (tid < 256) hist[tid] = 0;
        __syncthreads();
        const int shift = 24 - 8 * pass;
        for (int i = tid; i < neq; i += 1024) {
          const u32 vv = eqlist[i];
          if ((pb == 0) || ((vv >> (32 - pb)) == prefl)) atomicAdd(&hist[(vv >> shift) & 255], 1);
        }
        __syncthreads();
        if (tid == 0) {
          int cum = 0;
          int d = 255;
          for (; d >= 0; --d) {
            cum += hist[d];
            if (cum >= kn) break;
          }
          s_k = kn - (cum - hist[d]);
          s_pref = (prefl << 8) | (u32)d;
        }
        __syncthreads();
        prefl = s_pref;
        kn = s_k;
        pb += 8;
        __syncthreads();
      }
    }
    for (int i = tid; i < neq; i += 1024) {
      const u32 lo = eqlist[i];
      if (neq <= kneed || lo >= prefl) {
        const int pos = atomicAdd(&s_cnt, 1);
        if (pos < CAP) {
          const int tok = (int)(0xFFFFFFFFu - lo);
          idxl[e * CAP + pos] = tok;
          gatel[e * CAP + pos] = thrp_f;
          const int j = atomicAdd(tok_cnt + tok, 1);
          if (j < NE) tok_list[tok * NE + j] = e * CAP + pos;
        }
      }
    }
  } else {
    u64 pref64 = (u64)thrp;
    int pb64 = 32;
    int kn = kneed;
    for (int pass = 4; pass < 8; ++pass) {
      if (tid < 256) hist[tid] = 0;
      __syncthreads();
      const int shift = 56 - 8 * pass;
      for (int i = tid; i < T_TOK; i += 1024) {
        const u64 key = ke[i];
        if ((key >> (64 - pb64)) == pref64) atomicAdd(&hist[(int)((key >> shift) & 255)], 1);
      }
      __syncthreads();
      if (tid == 0) {
        int cum = 0;
        int d = 255;
        for (; d >= 0; --d) {
          cum += hist[d];
          if (cum >= kn) break;
        }
        s_k = kn - (cum - hist[d]);
        s_pref = (u32)d;
      }
      __syncthreads();
      pref64 = (pref64 << 8) | s_pref;
      kn = s_k;
      pb64 += 8;
      __syncthreads();
    }
    for (int i = tid; i < T_TOK; i += 1024) {
      const u64 key = ke[i];
      if ((u32)(key >> 32) == thrp && key >= pref64) {
        const int pos = atomicAdd(&s_cnt, 1);
        if (pos < CAP) {
          const int tok = (int)(0xFFFFFFFFu - (u32)key);
          idxl[e * CAP + pos] = tok;
          gatel[e * CAP + pos] = thrp_f;
          const int j = atomicAdd(tok_cnt + tok, 1);
          if (j < NE) tok_list[tok * NE + j] = e * CAP + pos;
        }
      }
    }
  }
}

// ---------------- fp32 -> bf16 conversion (fallback for EC<8 chunked path) ----------------
__global__ __launch_bounds__(256) void cvt2_kernel(
    const float* __restrict__ s1, __hip_bfloat16* __restrict__ d1,
    const float* __restrict__ s2, __hip_bfloat16* __restrict__ d2, int n4each) {
  int i = blockIdx.x * blockDim.x + threadIdx.x;
  const int stride = gridDim.x * blockDim.x;
  for (; i < 2 * n4each; i += stride) {
    const float* s = (i < n4each) ? s1 : s2;
    __hip_bfloat16* d = (i < n4each) ? d1 : d2;
    const int j = (i < n4each) ? i : i - n4each;
    const float4 v = reinterpret_cast<const float4*>(s)[j];
    ushort4 o;
    o.x = bf16_bits(v.x); o.y = bf16_bits(v.y);
    o.z = bf16_bits(v.z); o.w = bf16_bits(v.w);
    reinterpret_cast<ushort4*>(d)[j] = o;
  }
}

// ---------------- MFMA GEMM: 256x256 tile, 16 waves (4x4), 64x64/wave (R7 proven) ----------------
// 4-slot LDS ring, counted vmcnt, 2 coarse phases per K-tile.
// MODE 0: fc1  C = gather(xn, idx) @ w1^T -> bias+gelu -> hmid (bf16)
// MODE 1: fc2  C = hmid @ w2^T            -> bias, gate-weighted bf16 store to ye
template <int MODE>
__global__ __launch_bounds__(1024) void gemm7_kernel(
    const __hip_bfloat16* __restrict__ Asrc, const __hip_bfloat16* __restrict__ Bw,
    const float* __restrict__ bias, const int* __restrict__ idxl,
    const float* __restrict__ gatel, __hip_bfloat16* __restrict__ hmid,
    __hip_bfloat16* __restrict__ ye, int ebase) {
  constexpr int N = (MODE == 0) ? FF_DIM : H_DIM;
  constexpr int K = (MODE == 0) ? H_DIM : FF_DIM;
  constexpr int NBN = N / BN2;
  constexpr int LOG_NBN = (MODE == 0) ? 4 : 2;
  constexpr int BPE = (CAP / BM2) * NBN;
  constexpr int LOG_BPE = (MODE == 0) ? 7 : 5;
  constexpr int NT = K / BK2;

  const int nwg = gridDim.x;
  const int wg0 = blockIdx.x;
  const int wg = (wg0 & 7) * (nwg >> 3) + (wg0 >> 3);
  const int z = wg >> LOG_BPE;
  const int rr = wg & (BPE - 1);
  const int bm = rr >> LOG_NBN;
  const int bn = rr & (NBN - 1);
  const int e = ebase + z;

  const int tid = threadIdx.x;
  const int lane = tid & 63;
  const int w = tid >> 6;
  const int wr = w >> 2, wc = w & 3;  // 4x4 wave grid; wave owns 64x64
  const int fr = lane & 15, q = lane >> 4;

  __shared__ char smem[131072];  // 4 slots x 32KB: A@0 (256x32) B@16K (256x32)

  const int srow = tid >> 2;
  const int sg = tid & 3;
  const int skoff = (sg ^ ((srow >> 1) & 3)) * 8;

  const __hip_bfloat16* asrc;
  if constexpr (MODE == 0) {
    const int t0 = idxl[e * CAP + bm * BM2 + srow];
    asrc = Asrc + (size_t)t0 * H_DIM + skoff;
  } else {
    asrc = Asrc + ((size_t)z * CAP + bm * BM2 + srow) * FF_DIM + skoff;
  }
  const __hip_bfloat16* bsrc = Bw + (size_t)z * N * K + (size_t)(bn * BN2 + srow) * K + skoff;

  const int slotk = ((q ^ ((fr >> 1) & 3)) << 4);
  const int aoff0 = (wr * 64 + fr) * 64 + slotk;           // +m*1024 for m=0..3
  const int boff0 = 16384 + (wc * 64 + fr) * 64 + slotk;   // +n*1024 for n=0..3

  f32x4 acc[4][4] = {};
  bf16x8 Af[4], Bf[4];

#define GLDA(sb, k0) gload_lds16(asrc + (k0), smem + (sb)*32768 + tid * 16)
#define GLDB(sb, k0) gload_lds16(bsrc + (k0), smem + (sb)*32768 + 16384 + tid * 16)

  // prologue: stage tiles 0,1,2
  GLDA(0, 0); GLDB(0, 0);
  GLDA(1, BK2); GLDB(1, BK2);
  GLDA(2, 2 * BK2); GLDB(2, 2 * BK2);
  asm volatile("s_waitcnt vmcnt(4)");  // tile 0 resident
  __builtin_amdgcn_s_barrier();
  __builtin_amdgcn_sched_barrier(0);

  for (int kt = 0; kt < NT; ++kt) {
    const int cur = kt & 3;
    const int kref = (kt + 3 < NT) ? (kt + 3) : (kt + 3 - NT);  // wrapped (harmless)
    const int k0p = kref * BK2;
    const int psl = (kt + 3) & 3;
    const char* base = smem + cur * 32768;

    // ---- pA: 8 fragment reads (A0-3,B0,B1 first), A-prefetch, vmcnt(3), barrier
    Af[0] = *reinterpret_cast<const bf16x8*>(base + aoff0);
    Af[1] = *reinterpret_cast<const bf16x8*>(base + aoff0 + 1024);
    Af[2] = *reinterpret_cast<const bf16x8*>(base + aoff0 + 2048);
    Af[3] = *reinterpret_cast<const bf16x8*>(base + aoff0 + 3072);
    Bf[0] = *reinterpret_cast<const bf16x8*>(base + boff0);
    Bf[1] = *reinterpret_cast<const bf16x8*>(base + boff0 + 1024);
    __builtin_amdgcn_sched_barrier(0);  // pin: first 6 reads issue before last 2
    Bf[2] = *reinterpret_cast<const bf16x8*>(base + boff0 + 2048);
    Bf[3] = *reinterpret_cast<const bf16x8*>(base + boff0 + 3072);
    GLDA(psl, k0p);
    asm volatile("s_waitcnt vmcnt(3)");  // tile kt+1 fully resident
    __builtin_amdgcn_s_barrier();
    asm volatile("s_waitcnt lgkmcnt(2)");  // A0-3,B0,B1 ready; B2,B3 drain under MFMA
    __builtin_amdgcn_sched_barrier(0);
    __builtin_amdgcn_s_setprio(1);
#pragma unroll
    for (int m_ = 0; m_ < 4; ++m_) {
      acc[m_][0] = __builtin_amdgcn_mfma_f32_16x16x32_bf16(Af[m_], Bf[0], acc[m_][0], 0, 0, 0);
      acc[m_][1] = __builtin_amdgcn_mfma_f32_16x16x32_bf16(Af[m_], Bf[1], acc[m_][1], 0, 0, 0);
    }
    __builtin_amdgcn_s_setprio(0);
    __builtin_amdgcn_sched_barrier(0);

    // ---- pB: B-prefetch, drain reads pre-barrier (slot-reuse soundness), barrier
    GLDB(psl, k0p);
    asm volatile("s_waitcnt lgkmcnt(0)");
    __builtin_amdgcn_sched_barrier(0);
    __builtin_amdgcn_s_barrier();
    __builtin_amdgcn_sched_barrier(0);
    __builtin_amdgcn_s_setprio(1);
#pragma unroll
    for (int m_ = 0; m_ < 4; ++m_) {
      acc[m_][2] = __builtin_amdgcn_mfma_f32_16x16x32_bf16(Af[m_], Bf[2], acc[m_][2], 0, 0, 0);
      acc[m_][3] = __builtin_amdgcn_mfma_f32_16x16x32_bf16(Af[m_], Bf[3], acc[m_][3], 0, 0, 0);
    }
    __builtin_amdgcn_s_setprio(0);
    __builtin_amdgcn_sched_barrier(0);
  }
#undef GLDA
#undef GLDB

  if constexpr (MODE == 0) {
#pragma unroll
    for (int m = 0; m < 4; ++m) {
      const int rbase = bm * BM2 + wr * 64 + m * 16 + q * 4;
#pragma unroll
      for (int n = 0; n < 4; ++n) {
        const int gn = bn * BN2 + wc * 64 + n * 16 + fr;
        const float bb = bias[e * FF_DIM + gn];
#pragma unroll
        for (int i = 0; i < 4; ++i) {
          const float v = acc[m][n][i] + bb;
          const float u = v * (1.5957691216f + 0.0713548162972f * v * v);
          const float s = 1.0f / (1.0f + __expf(-u));
          hmid[((size_t)z * CAP + rbase + i) * FF_DIM + gn] = __float2bfloat16(v * s);
        }
      }
    }
  } else {
#pragma unroll
    for (int m = 0; m < 4; ++m) {
      const int rbase = bm * BM2 + wr * 64 + m * 16 + q * 4;
      float gt[4];
#pragma unroll
      for (int i = 0; i < 4; ++i) gt[i] = gatel[e * CAP + rbase + i];
#pragma unroll
      for (int n = 0; n < 4; ++n) {
        const int gn = bn * BN2 + wc * 64 + n * 16 + fr;
        const float bb = bias[e * H_DIM + gn];
#pragma unroll
        for (int i = 0; i < 4; ++i)
          ye[((size_t)e * CAP + rbase + i) * H_DIM + gn] =
              __float2bfloat16((acc[m][n][i] + bb) * gt[i]);
      }
    }
  }
}

// ---------------- combine: gather <=8 expert rows per token, sum, normalize ----------------
__global__ __launch_bounds__(256) void combine_kernel(
    const __hip_bfloat16* __restrict__ ye, const float* __restrict__ gatel,
    const int* __restrict__ tok_list, const int* __restrict__ tok_cnt,
    float* __restrict__ out) {
  const int t = blockIdx.x;
  const int tid = threadIdx.x;
  const int cnt = tok_cnt[t];
  float a0 = 0.f, a1 = 0.f, a2 = 0.f, a3 = 0.f, gs = 0.f;
  for (int j = 0; j < cnt && j < NE; ++j) {
    const int ent = tok_list[t * NE + j];
    gs += gatel[ent];
    const ushort4 v = reinterpret_cast<const ushort4*>(ye + (size_t)ent * H_DIM)[tid];
    a0 += bits_f32(v.x);
    a1 += bits_f32(v.y);
    a2 += bits_f32(v.z);
    a3 += bits_f32(v.w);
  }
  const float inv = 1.0f / fmaxf(gs, 1e-9f);
  float4 o;
  o.x = a0 * inv; o.y = a1 * inv; o.z = a2 * inv; o.w = a3 * inv;
  reinterpret_cast<float4*>(out + (size_t)t * H_DIM)[tid] = o;
}

extern "C" void kernel_launch(void* const* d_in, const int* in_sizes, int n_in,
                              void* d_out, int out_size, void* d_ws, size_t ws_size,
                              hipStream_t stream) {
  const float* x = (const float*)d_in[0];
  const float* nw = (const float*)d_in[1];
  const float* rw = (const float*)d_in[2];
  const float* rb = (const float*)d_in[3];
  const float* fc1w = (const float*)d_in[4];
  const float* fc1b = (const float*)d_in[5];
  const float* fc2w = (const float*)d_in[6];
  const float* fc2b = (const float*)d_in[7];
  float* out = (float*)d_out;

  char* ws = (char*)d_ws;
  size_t off = 0;
  auto alloc = [&](size_t b) {
    char* p = ws + off;
    off += (b + 255) & ~(size_t)255;
    return p;
  };
  __hip_bfloat16* xn = (__hip_bfloat16*)alloc((size_t)T_TOK * H_DIM * 2);
  u64* keys = (u64*)alloc((size_t)NE * T_TOK * 8);
  int* idxl = (int*)alloc((size_t)NE * CAP * 4);
  float* gatel = (float*)alloc((size_t)NE * CAP * 4);
  int* tok_list = (int*)alloc((size_t)T_TOK * NE * 4);
  int* tok_cnt = (int*)alloc((size_t)T_TOK * 4);
  __hip_bfloat16* ye = (__hip_bfloat16*)alloc((size_t)NE * CAP * H_DIM * 2);

  int EC = NE;
  while (EC > 1) {
    const size_t per = (size_t)EC * ((size_t)FF_DIM * H_DIM * 2 * 2 + (size_t)CAP * FF_DIM * 2);
    if (off + per + 4096 <= ws_size) break;
    EC >>= 1;
  }
  __hip_bfloat16* w1b = (__hip_bfloat16*)alloc((size_t)EC * FF_DIM * H_DIM * 2);
  __hip_bfloat16* w2b = (__hip_bfloat16*)alloc((size_t)EC * H_DIM * FF_DIM * 2);
  __hip_bfloat16* hmid = (__hip_bfloat16*)alloc((size_t)EC * CAP * FF_DIM * 2);

  const int fused_cvt = (EC == NE) ? 1 : 0;

  router_kernel<<<T_TOK, 256, 0, stream>>>(x, nw, rw, rb, xn, keys, tok_cnt,
                                           fc1w, w1b, fc2w, w2b, fused_cvt);
  topk_kernel<<<NE, 1024, 0, stream>>>(keys, idxl, gatel, tok_list, tok_cnt);

  for (int eb = 0; eb < NE; eb += EC) {
    if (!fused_cvt) {
      const int n4 = EC * FF_DIM * H_DIM / 4;
      cvt2_kernel<<<4096, 256, 0, stream>>>(fc1w + (size_t)eb * FF_DIM * H_DIM, w1b,
                                            fc2w + (size_t)eb * H_DIM * FF_DIM, w2b, n4);
    }
    const int nb1 = EC * (CAP / BM2) * (FF_DIM / BN2);
    gemm7_kernel<0><<<nb1, 1024, 0, stream>>>(xn, w1b, fc1b, idxl, gatel, hmid, ye, eb);
    const int nb2 = EC * (CAP / BM2) * (H_DIM / BN2);
    gemm7_kernel<1><<<nb2, 1024, 0, stream>>>(hmid, w2b, fc2b, idxl, gatel, hmid, ye, eb);
  }
  combine_kernel<<<T_TOK, 256, 0, stream>>>(ye, gatel, tok_list, tok_cnt, out);
}